// Round 9
// baseline (71.681 us; speedup 1.0000x reference)
//
#include <hip/hip_runtime.h>
#include <math.h>

typedef short bf16x8 __attribute__((ext_vector_type(8)));
typedef float f32x4 __attribute__((ext_vector_type(4)));

__device__ __forceinline__ int cvt2(float lo, float hi) {
    int r;
    asm("v_cvt_pk_bf16_f32 %0, %1, %2" : "=v"(r) : "v"(lo), "v"(hi));
    return r;
}

#define BAR() do {                                                        \
        asm volatile("s_waitcnt lgkmcnt(0)" ::: "memory");                \
        __builtin_amdgcn_s_barrier();                                     \
        __builtin_amdgcn_sched_barrier(0);                                \
    } while (0)

// Grid barrier, 256 co-resident blocks. R5 post-mortem: polling with ACQUIRE
// at agent scope emits an L2-invalidate PER POLL -> 255 spinners nuked every
// XCD's L2 (~115us/barrier). Fix: RELEASE fence (wbl2) once before arrival,
// RELAXED polls (L3 read, no invalidate), ACQUIRE fence (inv) once after
// release. The trailing inv also drops stale L2 lines (cross-XCD + previous
// graph replay) before the next phase reads res/f1p.
__device__ __forceinline__ void gsync(int* cnt, int* gen) {
    __syncthreads();
    if (threadIdx.x == 0) {
        __builtin_amdgcn_fence(__ATOMIC_RELEASE, "agent");   // wbl2: publish
        int g0 = __hip_atomic_load(gen, __ATOMIC_RELAXED, __HIP_MEMORY_SCOPE_AGENT);
        int v  = __hip_atomic_fetch_add(cnt, 1, __ATOMIC_RELAXED, __HIP_MEMORY_SCOPE_AGENT);
        if (v == 255) {
            __hip_atomic_fetch_add(gen, 1, __ATOMIC_RELAXED, __HIP_MEMORY_SCOPE_AGENT);
        } else {
            while (__hip_atomic_load(gen, __ATOMIC_RELAXED, __HIP_MEMORY_SCOPE_AGENT) == g0)
                __builtin_amdgcn_s_sleep(4);
        }
    }
    __syncthreads();
    __builtin_amdgcn_fence(__ATOMIC_ACQUIRE, "agent");       // inv: drop stale
}

__global__ void init_k(int* bar) {
    if (threadIdx.x < 4) bar[threadIdx.x] = 0;
}

// fc GEMM phase (R4 gemm_k body): out rows [rg*64,+64) cols [c0,+16)
// += act[128][1024] @ wgt[N][1024]^T ; split-K x2 via bb&1; atomic epilogue.
template<bool RELUA>
__device__ __forceinline__ void fc_phase(
    const float* __restrict__ act, const float* __restrict__ wgt,
    const float* __restrict__ bias, float* __restrict__ outp, int ldo,
    int bb, int tid, short* As0, short* As1, short* Ws0, short* Ws1)
{
    const int lane = tid & 63;
    const int wv   = tid >> 6;
    const int ks = bb & 1, rest = bb >> 1, rg = rest & 1, tile = rest >> 1;
    const int c0 = tile * 16, row0 = rg * 64, kt0 = ks * 8;
    const int r0 = tid >> 3, kc = tid & 7;
    const float* aP = act + (row0 + r0) * 1024 + kt0 * 64 + kc * 8;
    const float* wP = wgt + (c0 + r0) * 1024 + kt0 * 64 + kc * 8;
    const bool wAct = (tid < 128);
    const int sa0 = (r0 * 64 + kc * 8) ^ ((r0 & 7) << 3);
    const int sa1 = ((r0 + 32) * 64 + kc * 8) ^ ((r0 & 7) << 3);

    f32x4 A[4][4], W[4][2];
    f32x4 acc = {};

#define F_ISSUE(kt, s) do {                                               \
        A[s][0] = *(const f32x4*)(aP + (kt) * 64);                        \
        A[s][1] = *(const f32x4*)(aP + (kt) * 64 + 4);                    \
        A[s][2] = *(const f32x4*)(aP + (kt) * 64 + 32768);                \
        A[s][3] = *(const f32x4*)(aP + (kt) * 64 + 32772);                \
        if (wAct) {                                                       \
            W[s][0] = *(const f32x4*)(wP + (kt) * 64);                    \
            W[s][1] = *(const f32x4*)(wP + (kt) * 64 + 4);                \
        }                                                                 \
    } while (0)

#define RL(v) (RELUA ? fmaxf((v), 0.0f) : (v))

#define F_STAGE(s, AS, WS) do {                                           \
        int4 p0, p1;                                                      \
        p0.x = cvt2(RL(A[s][0][0]), RL(A[s][0][1]));                      \
        p0.y = cvt2(RL(A[s][0][2]), RL(A[s][0][3]));                      \
        p0.z = cvt2(RL(A[s][1][0]), RL(A[s][1][1]));                      \
        p0.w = cvt2(RL(A[s][1][2]), RL(A[s][1][3]));                      \
        p1.x = cvt2(RL(A[s][2][0]), RL(A[s][2][1]));                      \
        p1.y = cvt2(RL(A[s][2][2]), RL(A[s][2][3]));                      \
        p1.z = cvt2(RL(A[s][3][0]), RL(A[s][3][1]));                      \
        p1.w = cvt2(RL(A[s][3][2]), RL(A[s][3][3]));                      \
        *(int4*)&AS[sa0] = p0;                                            \
        *(int4*)&AS[sa1] = p1;                                            \
        if (wAct) {                                                       \
            int4 q;                                                       \
            q.x = cvt2(W[s][0][0], W[s][0][1]);                           \
            q.y = cvt2(W[s][0][2], W[s][0][3]);                           \
            q.z = cvt2(W[s][1][0], W[s][1][1]);                           \
            q.w = cvt2(W[s][1][2], W[s][1][3]);                           \
            *(int4*)&WS[sa0] = q;                                         \
        }                                                                 \
    } while (0)

#define F_COMPUTE(AS, WS) do {                                            \
        _Pragma("unroll")                                                 \
        for (int kk = 0; kk < 64; kk += 32) {                             \
            const int kw = kk + 8 * (lane >> 4);                          \
            const int ar = wv * 16 + (lane & 15);                         \
            bf16x8 af = *(const bf16x8*)&AS[(ar * 64 + kw) ^ ((ar & 7) << 3)]; \
            int br = lane & 15;                                           \
            bf16x8 bw = *(const bf16x8*)&WS[(br * 64 + kw) ^ ((br & 7) << 3)]; \
            acc = __builtin_amdgcn_mfma_f32_16x16x32_bf16(af, bw, acc, 0, 0, 0); \
        }                                                                 \
    } while (0)

    F_ISSUE(0, 0); F_ISSUE(1, 1); F_ISSUE(2, 2); F_ISSUE(3, 3);

    #pragma unroll 1
    for (int g = 0; g < 2; ++g) {
        const int kt = 4 * g;
        F_STAGE(0, As0, Ws0); if (kt + 4 < 8) F_ISSUE(kt + 4, 0); BAR(); F_COMPUTE(As0, Ws0);
        F_STAGE(1, As1, Ws1); if (kt + 5 < 8) F_ISSUE(kt + 5, 1); BAR(); F_COMPUTE(As1, Ws1);
        F_STAGE(2, As0, Ws0); if (kt + 6 < 8) F_ISSUE(kt + 6, 2); BAR(); F_COMPUTE(As0, Ws0);
        F_STAGE(3, As1, Ws1); if (kt + 7 < 8) F_ISSUE(kt + 7, 3); BAR(); F_COMPUTE(As1, Ws1);
    }

#undef F_ISSUE
#undef RL
#undef F_STAGE
#undef F_COMPUTE

    const int col = c0 + (lane & 15);
    const float bv = (ks == 0) ? bias[col] : 0.0f;
    #pragma unroll
    for (int r = 0; r < 4; ++r) {
        int row = row0 + wv * 16 + (lane >> 4) * 4 + r;
        unsafeAtomicAdd(&outp[row * ldo + col], acc[r] + bv);
    }
}

// ---------------------------------------------------------------------------
// One launch: phase1 gates+GRU (blocks 0..127; blocks 128..255 zero the
// split-K targets only — R6/R7 showed heavier helper traffic evicts L2 and
// regresses) | gsync | phase2 fc1 (all 256) | gsync | phase3 fc3 (blocks 0..63).
// Phase bodies are byte-for-byte round-4 (best known: 30.2us as 3 launches).
__global__ __launch_bounds__(256, 1) void fused_k(
    const float* __restrict__ x, const float* __restrict__ h1,
    const float* __restrict__ w_ih, const float* __restrict__ w_hh,
    const float* __restrict__ b_ih, const float* __restrict__ b_hh,
    const float* __restrict__ w_fc1, const float* __restrict__ b_fc1,
    const float* __restrict__ w_fc3, const float* __restrict__ b_fc3,
    float* __restrict__ out, float* __restrict__ h1p,
    float* __restrict__ res, float* __restrict__ f1p, int* bar)
{
    __shared__ short As[2][128 * 64];   // 32 KB (phases 2/3 use a 64x64 subset)
    __shared__ short Ws[2][96 * 64];    // 24 KB (phases 2/3 use a 16x64 subset)
    const int tid  = threadIdx.x;
    const int lane = tid & 63;
    const int wv   = tid >> 6;
    const int b    = blockIdx.x;

    // ================= phase 1 =================
    if (b >= 128) {
        // idle blocks: zero split-K atomic targets (640 KB total, light)
        const int w = b - 128;            // 0..127
        f32x4 z = {};
        *(f32x4*)(f1p + w * 1024 + tid * 4) = z;
        if (tid < 64) *(f32x4*)(out + w * 256 + tid * 4) = z;
    } else {
        const int tile = b & 63;          // b / b+64 share XCD (64 % 8 == 0)
        const int rg   = b >> 6;
        const int c0   = tile * 16;
        const int row0 = rg * 64;
        const int r0 = tid >> 3, kc = tid & 7;

        const float* aP[4];
        int saI[4];
        #pragma unroll
        for (int i = 0; i < 4; ++i) {
            int ma = r0 + 32 * i;                         // 0..127
            const float* src = (i < 2) ? x : h1;
            aP[i] = src + (row0 + (ma & 63)) * 1024 + kc * 8;
            saI[i] = (ma * 64 + kc * 8) ^ ((ma & 7) << 3);
        }
        const float* wP[3];
        int swI[3];
        #pragma unroll
        for (int i = 0; i < 3; ++i) {
            int mw = r0 + 32 * i;                         // 0..95
            int g = mw >> 4;                              // gate 0..5
            const float* src = (g < 3) ? w_ih : w_hh;
            wP[i] = src + ((g % 3) * 1024 + c0 + (mw & 15)) * 1024 + kc * 8;
            swI[i] = (mw * 64 + kc * 8) ^ ((mw & 7) << 3);
        }

        f32x4 A[2][4][2], W[2][3][2];
        f32x4 acc[6] = {};

#define G_ISSUE(kt, s) do {                                               \
        _Pragma("unroll")                                                 \
        for (int i = 0; i < 4; ++i) {                                     \
            A[s][i][0] = *(const f32x4*)(aP[i] + (kt) * 64);              \
            A[s][i][1] = *(const f32x4*)(aP[i] + (kt) * 64 + 4);          \
        }                                                                 \
        _Pragma("unroll")                                                 \
        for (int i = 0; i < 3; ++i) {                                     \
            W[s][i][0] = *(const f32x4*)(wP[i] + (kt) * 64);              \
            W[s][i][1] = *(const f32x4*)(wP[i] + (kt) * 64 + 4);          \
        }                                                                 \
    } while (0)

#define G_STAGE(s, bb) do {                                               \
        _Pragma("unroll")                                                 \
        for (int i = 0; i < 4; ++i) {                                     \
            int4 p;                                                       \
            p.x = cvt2(A[s][i][0][0], A[s][i][0][1]);                     \
            p.y = cvt2(A[s][i][0][2], A[s][i][0][3]);                     \
            p.z = cvt2(A[s][i][1][0], A[s][i][1][1]);                     \
            p.w = cvt2(A[s][i][1][2], A[s][i][1][3]);                     \
            *(int4*)&As[bb][saI[i]] = p;                                  \
        }                                                                 \
        _Pragma("unroll")                                                 \
        for (int i = 0; i < 3; ++i) {                                     \
            int4 q;                                                       \
            q.x = cvt2(W[s][i][0][0], W[s][i][0][1]);                     \
            q.y = cvt2(W[s][i][0][2], W[s][i][0][3]);                     \
            q.z = cvt2(W[s][i][1][0], W[s][i][1][1]);                     \
            q.w = cvt2(W[s][i][1][2], W[s][i][1][3]);                     \
            *(int4*)&Ws[bb][swI[i]] = q;                                  \
        }                                                                 \
    } while (0)

#define G_COMPUTE(bb) do {                                                \
        _Pragma("unroll")                                                 \
        for (int kk = 0; kk < 64; kk += 32) {                             \
            const int kw = kk + 8 * (lane >> 4);                          \
            const int ar = wv * 16 + (lane & 15);                         \
            bf16x8 afx = *(const bf16x8*)&As[bb][(ar * 64 + kw) ^ ((ar & 7) << 3)]; \
            bf16x8 afh = *(const bf16x8*)&As[bb][((ar + 64) * 64 + kw) ^ ((ar & 7) << 3)]; \
            _Pragma("unroll")                                             \
            for (int g = 0; g < 6; ++g) {                                 \
                int br = g * 16 + (lane & 15);                            \
                bf16x8 bw = *(const bf16x8*)&Ws[bb][(br * 64 + kw) ^ ((br & 7) << 3)]; \
                acc[g] = __builtin_amdgcn_mfma_f32_16x16x32_bf16(         \
                    (g < 3) ? afx : afh, bw, acc[g], 0, 0, 0);            \
            }                                                             \
        }                                                                 \
    } while (0)

        G_ISSUE(0, 0); G_ISSUE(1, 1);
        #pragma unroll 1
        for (int kt2 = 0; kt2 < 8; ++kt2) {
            const int kt = 2 * kt2;
            G_STAGE(0, 0); if (kt + 2 < 16) G_ISSUE(kt + 2, 0); BAR(); G_COMPUTE(0);
            G_STAGE(1, 1); if (kt + 3 < 16) G_ISSUE(kt + 3, 1); BAR(); G_COMPUTE(1);
        }
#undef G_ISSUE
#undef G_STAGE
#undef G_COMPUTE

        // GRU epilogue in-register
        const int j = c0 + (lane & 15);
        const float bir = b_ih[j], biz = b_ih[1024 + j], bin = b_ih[2048 + j];
        const float bhr = b_hh[j], bhz = b_hh[1024 + j], bhn = b_hh[2048 + j];
        const int rbase = row0 + wv * 16 + (lane >> 4) * 4;
        #pragma unroll
        for (int r = 0; r < 4; ++r) {
            const int row = rbase + r;
            float ir  = acc[0][r] + bir, iz = acc[1][r] + biz, inn = acc[2][r] + bin;
            float hr  = acc[3][r] + bhr, hz = acc[4][r] + bhz, hn  = acc[5][r] + bhn;
            float rr = 1.0f / (1.0f + __expf(-(ir + hr)));
            float zz = 1.0f / (1.0f + __expf(-(iz + hz)));
            float nn = tanhf(inn + rr * hn);
            float h1v = h1[row * 1024 + j];
            float hp  = (1.0f - zz) * nn + zz * h1v;
            h1p[row * 1024 + j] = hp;
            res[row * 1024 + j] = hp + x[row * 1024 + j];
        }
    }

    gsync(bar, bar + 1);

    // ================= phase 2: fc1 (all 256 blocks) =================
    fc_phase<false>(res, w_fc1, b_fc1, f1p, 1024, b, tid,
                    As[0], As[1], Ws[0], Ws[1]);

    gsync(bar + 2, bar + 3);

    // ================= phase 3: fc3 (blocks 0..63) =================
    if (b < 64) {
        fc_phase<true>(f1p, w_fc3, b_fc3, out, 256, b, tid,
                       As[0], As[1], Ws[0], Ws[1]);
    }
}

extern "C" void kernel_launch(void* const* d_in, const int* in_sizes, int n_in,
                              void* d_out, int out_size, void* d_ws, size_t ws_size,
                              hipStream_t stream)
{
    const float* x     = (const float*)d_in[0];
    const float* h1    = (const float*)d_in[1];
    const float* w_ih  = (const float*)d_in[2];
    const float* w_hh  = (const float*)d_in[3];
    const float* b_ih  = (const float*)d_in[4];
    const float* b_hh  = (const float*)d_in[5];
    const float* w_fc1 = (const float*)d_in[6];
    const float* b_fc1 = (const float*)d_in[7];
    const float* w_fc3 = (const float*)d_in[8];
    const float* b_fc3 = (const float*)d_in[9];

    float* out = (float*)d_out;          // [128][256]
    float* h1p = out + 128 * 256;        // [128][1024]

    float* ws  = (float*)d_ws;
    float* res = ws;                     // [128][1024]
    float* f1p = ws + 131072;            // [128][1024]
    int*   bar = (int*)(ws + 262144);    // 4 ints barrier state

    init_k<<<1, 64, 0, stream>>>(bar);
    fused_k<<<256, 256, 0, stream>>>(x, h1, w_ih, w_hh, b_ih, b_hh,
                                     w_fc1, b_fc1, w_fc3, b_fc3,
                                     out, h1p, res, f1p, bar);
}

// Round 10
// 24.802 us; speedup vs baseline: 2.8901x; 2.8901x over previous
//
#include <hip/hip_runtime.h>
#include <math.h>

typedef short bf16x8 __attribute__((ext_vector_type(8)));
typedef float f32x4 __attribute__((ext_vector_type(4)));

__device__ __forceinline__ int cvt2(float lo, float hi) {
    int r;
    asm("v_cvt_pk_bf16_f32 %0, %1, %2" : "=v"(r) : "v"(lo), "v"(hi));
    return r;
}

#define BAR() do {                                                        \
        asm volatile("s_waitcnt lgkmcnt(0)" ::: "memory");                \
        __builtin_amdgcn_s_barrier();                                     \
        __builtin_amdgcn_sched_barrier(0);                                \
    } while (0)

// ---------------------------------------------------------------------------
// Fused gates GEMM + GRU. grid 256 (ALL CUs): block = (tile 0..63, rgq 0..3)
// -> 32 rows x 16 cols. The four rgq of a tile share b%8 (64%8==0) -> same
// XCD -> W re-reads are L2 hits. Wave mapping: wv = (rowg = wv&1,
// gate-trio = (wv>>1)*3): per kk each wave reads 1 A-frag + 3 W-frags
// (halves LDS read traffic vs the R4 6-gate-per-wave layout). GRU epilogue
// exchanges the h-gate accumulators through 6 KB of LDS.
// K-loop schedule: byte-for-byte R4 (2-deep register prefetch, 16 steps,
// double-buffered LDS, lgkm-only barriers). R8 lesson: schedule is pinned.
__global__ __launch_bounds__(256, 2) void gates_k(
    const float* __restrict__ x, const float* __restrict__ h1,
    const float* __restrict__ w_ih, const float* __restrict__ w_hh,
    const float* __restrict__ b_ih, const float* __restrict__ b_hh,
    float* __restrict__ h1p, float* __restrict__ res,
    float* __restrict__ zf1p, float* __restrict__ zout)
{
    __shared__ short As[2][64 * 64];    // 16 KB: meta-rows 0..31 = x, 32..63 = h1
    __shared__ short Ws[2][96 * 64];    // 24 KB: meta-row g*16+jr, gates 0..5
    const int tid  = threadIdx.x;
    const int lane = tid & 63;
    const int wv   = tid >> 6;
    const int b    = blockIdx.x;

    // zero split-K atomic targets (spread over all 256 blocks)
    if (tid < 128) { f32x4 z = {}; *(f32x4*)(zf1p + b * 512 + tid * 4) = z; }
    if (tid < 32)  { f32x4 z = {}; *(f32x4*)(zout + b * 128 + tid * 4) = z; }

    const int tile = b & 63;
    const int rgq  = b >> 6;              // 0..3
    const int c0   = tile * 16;
    const int row0 = rgq * 32;
    const int r0 = tid >> 3, kc = tid & 7;

    // A staging: 2 meta-rows/thread (x row, h1 row)
    const float* aP[2] = { x  + (row0 + r0) * 1024 + kc * 8,
                           h1 + (row0 + r0) * 1024 + kc * 8 };
    const int saI[2] = { (r0 * 64 + kc * 8) ^ ((r0 & 7) << 3),
                         ((r0 + 32) * 64 + kc * 8) ^ ((r0 & 7) << 3) };
    // W staging: 3 meta-rows/thread (unchanged from R4)
    const float* wP[3];
    int swI[3];
    #pragma unroll
    for (int i = 0; i < 3; ++i) {
        int mw = r0 + 32 * i;                         // 0..95
        int g = mw >> 4;                              // gate 0..5
        const float* src = (g < 3) ? w_ih : w_hh;
        wP[i] = src + ((g % 3) * 1024 + c0 + (mw & 15)) * 1024 + kc * 8;
        swI[i] = (mw * 64 + kc * 8) ^ ((mw & 7) << 3);
    }

    f32x4 A[2][2][2], W[2][3][2];
    f32x4 acc[3] = {};

    const int rowg = wv & 1;              // 16-row group within the 32 rows
    const int hsel = wv >> 1;             // 0: gates 0-2 (i_*), 1: gates 3-5 (h_*)
    const int gbase = hsel * 3;

#define G_ISSUE(kt, s) do {                                               \
        _Pragma("unroll")                                                 \
        for (int i = 0; i < 2; ++i) {                                     \
            A[s][i][0] = *(const f32x4*)(aP[i] + (kt) * 64);              \
            A[s][i][1] = *(const f32x4*)(aP[i] + (kt) * 64 + 4);          \
        }                                                                 \
        _Pragma("unroll")                                                 \
        for (int i = 0; i < 3; ++i) {                                     \
            W[s][i][0] = *(const f32x4*)(wP[i] + (kt) * 64);              \
            W[s][i][1] = *(const f32x4*)(wP[i] + (kt) * 64 + 4);          \
        }                                                                 \
    } while (0)

#define G_STAGE(s, bb) do {                                               \
        _Pragma("unroll")                                                 \
        for (int i = 0; i < 2; ++i) {                                     \
            int4 p;                                                       \
            p.x = cvt2(A[s][i][0][0], A[s][i][0][1]);                     \
            p.y = cvt2(A[s][i][0][2], A[s][i][0][3]);                     \
            p.z = cvt2(A[s][i][1][0], A[s][i][1][1]);                     \
            p.w = cvt2(A[s][i][1][2], A[s][i][1][3]);                     \
            *(int4*)&As[bb][saI[i]] = p;                                  \
        }                                                                 \
        _Pragma("unroll")                                                 \
        for (int i = 0; i < 3; ++i) {                                     \
            int4 q;                                                       \
            q.x = cvt2(W[s][i][0][0], W[s][i][0][1]);                     \
            q.y = cvt2(W[s][i][0][2], W[s][i][0][3]);                     \
            q.z = cvt2(W[s][i][1][0], W[s][i][1][1]);                     \
            q.w = cvt2(W[s][i][1][2], W[s][i][1][3]);                     \
            *(int4*)&Ws[bb][swI[i]] = q;                                  \
        }                                                                 \
    } while (0)

#define G_COMPUTE(bb) do {                                                \
        _Pragma("unroll")                                                 \
        for (int kk = 0; kk < 64; kk += 32) {                             \
            const int kw = kk + 8 * (lane >> 4);                          \
            const int ma = hsel * 32 + rowg * 16 + (lane & 15);           \
            bf16x8 af = *(const bf16x8*)&As[bb][(ma * 64 + kw) ^ ((ma & 7) << 3)]; \
            _Pragma("unroll")                                             \
            for (int gg = 0; gg < 3; ++gg) {                              \
                int br = (gbase + gg) * 16 + (lane & 15);                 \
                bf16x8 bw = *(const bf16x8*)&Ws[bb][(br * 64 + kw) ^ ((br & 7) << 3)]; \
                acc[gg] = __builtin_amdgcn_mfma_f32_16x16x32_bf16(        \
                    af, bw, acc[gg], 0, 0, 0);                            \
            }                                                             \
        }                                                                 \
    } while (0)

    G_ISSUE(0, 0); G_ISSUE(1, 1);
    #pragma unroll 1
    for (int kt2 = 0; kt2 < 8; ++kt2) {
        const int kt = 2 * kt2;
        G_STAGE(0, 0); if (kt + 2 < 16) G_ISSUE(kt + 2, 0); BAR(); G_COMPUTE(0);
        G_STAGE(1, 1); if (kt + 3 < 16) G_ISSUE(kt + 3, 1); BAR(); G_COMPUTE(1);
    }
#undef G_ISSUE
#undef G_STAGE
#undef G_COMPUTE

    // ---- GRU epilogue: waves 2/3 export h-gates via LDS; waves 0/1 combine.
    // As[0] is free: its last reads (kt=14, buffer 0) were barriered before
    // the final COMPUTE(1). 6 KB used of 16 KB.
    float* xch = (float*)&As[0][0];
    if (hsel) {
        #pragma unroll
        for (int gg = 0; gg < 3; ++gg)
            #pragma unroll
            for (int r = 0; r < 4; ++r)
                xch[(rowg * 3 + gg) * 256 + ((lane >> 4) * 4 + r) * 16 + (lane & 15)]
                    = acc[gg][r];
    }
    BAR();
    if (!hsel) {
        const int j = c0 + (lane & 15);
        const float bir = b_ih[j], biz = b_ih[1024 + j], bin = b_ih[2048 + j];
        const float bhr = b_hh[j], bhz = b_hh[1024 + j], bhn = b_hh[2048 + j];
        const int rbase = row0 + rowg * 16 + (lane >> 4) * 4;
        #pragma unroll
        for (int r = 0; r < 4; ++r) {
            const int row = rbase + r;
            const int xb  = rowg * 3 * 256 + ((lane >> 4) * 4 + r) * 16 + (lane & 15);
            float ir  = acc[0][r] + bir, iz = acc[1][r] + biz, inn = acc[2][r] + bin;
            float hr  = xch[xb] + bhr, hz = xch[xb + 256] + bhz, hn = xch[xb + 512] + bhn;
            float rr = 1.0f / (1.0f + __expf(-(ir + hr)));
            float zz = 1.0f / (1.0f + __expf(-(iz + hz)));
            float nn = tanhf(inn + rr * hn);
            float h1v = h1[row * 1024 + j];
            float hp  = (1.0f - zz) * nn + zz * h1v;
            h1p[row * 1024 + j] = hp;
            res[row * 1024 + j] = hp + x[row * 1024 + j];
        }
    }
}

// ---------------------------------------------------------------------------
// Generic tiled GEMM (fc1 / fc3): out rows [rg*64,+64) cols [c0,+NT)
// (+)= act[128][1024] @ wgt[N][1024]^T ; split-K via ksbits + atomics.
// (byte-for-byte the round-4 version — known good)
template<int NT, bool ATOMIC, bool RELUA>
__global__ __launch_bounds__(256, 2) void gemm_k(
    const float* __restrict__ act, const float* __restrict__ wgt,
    const float* __restrict__ bias,
    float* __restrict__ out, int ldo, int nkt, int ksbits)
{
    constexpr int CT = NT / 16;
    __shared__ short As[2][64 * 64];
    __shared__ short Ws[2][NT * 64];

    const int tid  = threadIdx.x;
    const int lane = tid & 63;
    const int wv   = tid >> 6;

    const int ks   = blockIdx.x & ((1 << ksbits) - 1);
    const int rest = blockIdx.x >> ksbits;
    const int rg   = rest & 1;
    const int tile = rest >> 1;
    const int c0   = tile * NT;
    const int row0 = rg * 64;
    const int kt0  = ks * nkt;

    const int r0 = tid >> 3, kc = tid & 7;
    const float* aP = act + (row0 + r0) * 1024 + kt0 * 64 + kc * 8;
    const float* wP = wgt + (c0 + r0) * 1024 + kt0 * 64 + kc * 8;
    const bool wAct = (tid < NT * 8);

    const int saI0 = (r0 * 64 + kc * 8) ^ ((r0 & 7) << 3);
    const int saI1 = ((r0 + 32) * 64 + kc * 8) ^ ((r0 & 7) << 3);

    f32x4 A[4][4], W[4][2];
    f32x4 acc[CT] = {};

#define ISSUE(kt, s) do {                                                 \
        A[s][0] = *(const f32x4*)(aP + (kt) * 64);                        \
        A[s][1] = *(const f32x4*)(aP + (kt) * 64 + 4);                    \
        A[s][2] = *(const f32x4*)(aP + (kt) * 64 + 32768);                \
        A[s][3] = *(const f32x4*)(aP + (kt) * 64 + 32772);                \
        if (wAct) {                                                       \
            W[s][0] = *(const f32x4*)(wP + (kt) * 64);                    \
            W[s][1] = *(const f32x4*)(wP + (kt) * 64 + 4);                \
        }                                                                 \
    } while (0)

#define RL(v) (RELUA ? fmaxf((v), 0.0f) : (v))

#define STAGE(s, b) do {                                                  \
        int4 p0, p1;                                                      \
        p0.x = cvt2(RL(A[s][0][0]), RL(A[s][0][1]));                      \
        p0.y = cvt2(RL(A[s][0][2]), RL(A[s][0][3]));                      \
        p0.z = cvt2(RL(A[s][1][0]), RL(A[s][1][1]));                      \
        p0.w = cvt2(RL(A[s][1][2]), RL(A[s][1][3]));                      \
        p1.x = cvt2(RL(A[s][2][0]), RL(A[s][2][1]));                      \
        p1.y = cvt2(RL(A[s][2][2]), RL(A[s][2][3]));                      \
        p1.z = cvt2(RL(A[s][3][0]), RL(A[s][3][1]));                      \
        p1.w = cvt2(RL(A[s][3][2]), RL(A[s][3][3]));                      \
        *(int4*)&As[b][saI0] = p0;                                        \
        *(int4*)&As[b][saI1] = p1;                                        \
        if (wAct) {                                                       \
            int4 q;                                                       \
            q.x = cvt2(W[s][0][0], W[s][0][1]);                           \
            q.y = cvt2(W[s][0][2], W[s][0][3]);                           \
            q.z = cvt2(W[s][1][0], W[s][1][1]);                           \
            q.w = cvt2(W[s][1][2], W[s][1][3]);                           \
            *(int4*)&Ws[b][saI0] = q;                                     \
        }                                                                 \
    } while (0)

#define COMPUTE(b) do {                                                   \
        _Pragma("unroll")                                                 \
        for (int kk = 0; kk < 64; kk += 32) {                             \
            const int kw = kk + 8 * (lane >> 4);                          \
            const int ar = wv * 16 + (lane & 15);                         \
            bf16x8 af = *(const bf16x8*)&As[b][(ar * 64 + kw) ^ ((ar & 7) << 3)]; \
            bf16x8 bw[CT];                                                \
            _Pragma("unroll")                                             \
            for (int ct = 0; ct < CT; ++ct) {                             \
                int br = ct * 16 + (lane & 15);                           \
                bw[ct] = *(const bf16x8*)&Ws[b][(br * 64 + kw) ^ ((br & 7) << 3)]; \
            }                                                             \
            _Pragma("unroll")                                             \
            for (int ct = 0; ct < CT; ++ct)                               \
                acc[ct] = __builtin_amdgcn_mfma_f32_16x16x32_bf16(        \
                    af, bw[ct], acc[ct], 0, 0, 0);                        \
        }                                                                 \
    } while (0)

    ISSUE(0, 0); ISSUE(1, 1); ISSUE(2, 2); ISSUE(3, 3);

    #pragma unroll 1
    for (int g = 0; g < nkt / 4; ++g) {
        const int kt = 4 * g;
        STAGE(0, 0); if (kt + 4 < nkt) ISSUE(kt + 4, 0); BAR(); COMPUTE(0);
        STAGE(1, 1); if (kt + 5 < nkt) ISSUE(kt + 5, 1); BAR(); COMPUTE(1);
        STAGE(2, 0); if (kt + 6 < nkt) ISSUE(kt + 6, 2); BAR(); COMPUTE(0);
        STAGE(3, 1); if (kt + 7 < nkt) ISSUE(kt + 7, 3); BAR(); COMPUTE(1);
    }

#undef ISSUE
#undef RL
#undef STAGE
#undef COMPUTE

    #pragma unroll
    for (int ct = 0; ct < CT; ++ct) {
        int col = c0 + ct * 16 + (lane & 15);
        float bv = (bias && ks == 0) ? bias[col] : 0.0f;
        #pragma unroll
        for (int r = 0; r < 4; ++r) {
            int row = row0 + wv * 16 + (lane >> 4) * 4 + r;
            float v = acc[ct][r] + bv;
            if (ATOMIC) unsafeAtomicAdd(&out[row * ldo + col], v);
            else        out[row * ldo + col] = v;
        }
    }
}

extern "C" void kernel_launch(void* const* d_in, const int* in_sizes, int n_in,
                              void* d_out, int out_size, void* d_ws, size_t ws_size,
                              hipStream_t stream)
{
    const float* x     = (const float*)d_in[0];
    const float* h1    = (const float*)d_in[1];
    const float* w_ih  = (const float*)d_in[2];
    const float* w_hh  = (const float*)d_in[3];
    const float* b_ih  = (const float*)d_in[4];
    const float* b_hh  = (const float*)d_in[5];
    const float* w_fc1 = (const float*)d_in[6];
    const float* b_fc1 = (const float*)d_in[7];
    const float* w_fc3 = (const float*)d_in[8];
    const float* b_fc3 = (const float*)d_in[9];

    float* out = (float*)d_out;          // [128][256]
    float* h1p = out + 128 * 256;        // [128][1024]

    float* ws  = (float*)d_ws;
    float* res = ws;                     // [128][1024] h1' + x
    float* f1p = ws + 128 * 1024;        // [128][1024] fc1 pre-activation

    // fused gates GEMM + GRU -> h1p (d_out) and res; zeroes f1p and out
    gates_k<<<256, 256, 0, stream>>>(x, h1, w_ih, w_hh, b_ih, b_hh,
                                     h1p, res, f1p, out);
    // f1p += res @ w_fc1^T + b_fc1   (64 tiles x 2 rg x 4 ks = 512 blocks, 4 steps)
    gemm_k<16, true, false><<<512, 256, 0, stream>>>(
        res, w_fc1, b_fc1, f1p, 1024, 4, 2);
    // out += relu(f1p) @ w_fc3^T + b_fc3  (16 x 2 x 4 = 128 blocks, 4 steps)
    gemm_k<16, true, true><<<128, 256, 0, stream>>>(
        f1p, w_fc3, b_fc3, out, 256, 4, 2);
}